// Round 27
// baseline (57.119 us; speedup 1.0000x reference)
//
#include <hip/hip_runtime.h>

// R23: R22 (39.3us, verified absmax 4) with the reduction tree replaced by a
// native agent-scope fp32 atomic epilogue (gfx950 global_atomic_add_f32 via
// __hip_atomic_fetch_add AGENT — NOT plain atomicAdd's CAS loop, cf. R3).
// Kernels 4 -> 3: zero_out, bounds_build, virial_mfma(+atomics).
// Main loop / M/Dt/MFMA body byte-identical to R22.

#define NG 64
#define NCOMP 6
#define NPART (NG * NCOMP)      // 384
#define MFMA_BLOCKS 1024        // 4 blocks/CU
#define WPB 4
#define MROW 72                 // 64 + 8 pad ushorts; 144B rows (16B-aligned)
#define DROW 72
#define DTROWS 6                // only rows 0..5 real (C cols 6..15 discarded)

typedef unsigned short u16_t;
typedef unsigned int   u32_t;
typedef __attribute__((ext_vector_type(8))) short short8;
typedef __attribute__((ext_vector_type(4))) float f32x4;

__device__ __forceinline__ u16_t f2bf(float f) {
    union { float f; u32_t u; } v; v.f = f;
    u32_t r = v.u + 0x7FFFu + ((v.u >> 16) & 1u);
    return (u16_t)(r >> 16);
}

__device__ __forceinline__ void lds_add(float* p, float v) {
    __hip_atomic_fetch_add(p, v, __ATOMIC_RELAXED, __HIP_MEMORY_SCOPE_WORKGROUP);
}

// graph(a) = max{g : Bs[g] <= a}; Bs non-decreasing, Bs[64] = N sentinel.
__device__ __forceinline__ int gsearch(const int* Bs, int a) {
    int lo = 0;
#pragma unroll
    for (int st = 32; st >= 1; st >>= 1)
        lo += (Bs[lo + st] <= a) ? st : 0;
    return lo;
}

// ---------------- bounds table: B[g] = lower_bound(batch, g) ----------------
__global__ void bounds_build(const int* __restrict__ batch, int* __restrict__ B,
                             int N)
{
    int g = threadIdx.x;
    if (g > 64) return;
    int lo = 0, len = N;
    while (len > 0) {
        int half = len >> 1;
        int mid  = lo + half;
        if (batch[mid] < g) { lo = mid + 1; len -= half + 1; }
        else                { len = half; }
    }
    B[g] = lo;   // g=64 -> N (sentinel)
}

__global__ void zero_out_kernel(float* __restrict__ out, int n) {
    int i = blockIdx.x * blockDim.x + threadIdx.x;
    if (i < n) out[i] = 0.f;
}

// ---------------- MFMA main kernel ----------------
__global__ __launch_bounds__(256) void virial_mfma(
    const float* __restrict__ disp, const float* __restrict__ edge_w,
    const int* __restrict__ edge_index, const int* __restrict__ Bg,
    float* __restrict__ out, int E)
{
    __shared__ u16_t Msh[WPB][NG * MROW];      // 36864 B (reused as f32 stage)
    __shared__ u16_t Dsh[WPB][DTROWS * DROW];  //  3456 B
    __shared__ int   Bs[65];                   //   260 B

    const int lane = threadIdx.x & 63;
    const int wave = threadIdx.x >> 6;
    u16_t* Mw = Msh[wave];
    u16_t* Dw = Dsh[wave];

    if (threadIdx.x < 65) Bs[threadIdx.x] = Bg[threadIdx.x];
    {   // zero per-wave M and Dt (same-wave DS ops are in order)
        u32_t* p = (u32_t*)Mw;
        for (int i = lane; i < NG * MROW / 2; i += 64) p[i] = 0u;
        u32_t* q = (u32_t*)Dw;
        for (int i = lane; i < DTROWS * DROW / 2; i += 64) q[i] = 0u;
    }
    __syncthreads();   // Bs ready

    f32x4 acc0 = {0,0,0,0}, acc1 = {0,0,0,0}, acc2 = {0,0,0,0}, acc3 = {0,0,0,0};
    const int ngroups = (E + 63) >> 6;
    const int gstride = (int)gridDim.x * WPB;
    const int c_l = lane & 15;
    const int k4  = lane >> 4;
    const int drow = (c_l < DTROWS) ? c_l : (DTROWS - 1);  // junk -> discarded C cols
    int pg0 = 0, pg1 = 0;

    int grp = (int)blockIdx.x * WPB + wave;

    // 1-deep prefetch of the streaming loads (w, disp, idx) — no gathers
    float pw = 0.f, px = 0.f, py = 0.f, pz = 0.f;
    int   ps = 0, pt = 0;
    if (grp < ngroups) {
        int e  = grp * 64 + lane;
        int ec = e < E ? e : E - 1;
        pw = (e < E) ? edge_w[ec] : 0.f;   // w=0 kills clamped-tail terms
        px = disp[ec * 3 + 0];
        py = disp[ec * 3 + 1];
        pz = disp[ec * 3 + 2];
        ps = edge_index[ec];
        pt = edge_index[E + ec];
    }

    while (grp < ngroups) {
        const float w = pw, d0 = px, d1 = py, d2 = pz;
        const int   sC = ps, tC = pt;

        const int nxt = grp + gstride;
        if (nxt < ngroups) {
            int e  = nxt * 64 + lane;
            int ec = e < E ? e : E - 1;
            pw = (e < E) ? edge_w[ec] : 0.f;
            px = disp[ec * 3 + 0];
            py = disp[ec * 3 + 1];
            pz = disp[ec * 3 + 2];
            ps = edge_index[ec];
            pt = edge_index[E + ec];
        }

        // gather-free endpoint->graph: 6-step ladder over LDS table
        const int g0 = gsearch(Bs, sC);
        const int g1 = gsearch(Bs, tC);

        // --- R10-verified body ---
        Mw[pg0 * MROW + lane] = 0;
        Mw[pg1 * MROW + lane] = 0;
        Mw[g0 * MROW + lane] = 0x3F80u;                          // 1.0
        Mw[g1 * MROW + lane] = (g1 == g0) ? 0x4000u : 0x3F80u;   // 2.0 / 1.0
        pg0 = g0; pg1 = g1;

        float cw = -2.f * w;
        Dw[0 * DROW + lane] = f2bf(cw * d0 * d0);
        Dw[1 * DROW + lane] = f2bf(cw * d0 * d1);
        Dw[2 * DROW + lane] = f2bf(cw * d0 * d2);
        Dw[3 * DROW + lane] = f2bf(cw * d1 * d1);
        Dw[4 * DROW + lane] = f2bf(cw * d1 * d2);
        Dw[5 * DROW + lane] = f2bf(cw * d2 * d2);

#pragma unroll
        for (int half = 0; half < 2; ++half) {
            const int kb = half * 32 + k4 * 8;
            short8 bf = *(const short8*)&Dw[drow * DROW + kb];
            short8 a0 = *(const short8*)&Mw[( 0 + c_l) * MROW + kb];
            short8 a1 = *(const short8*)&Mw[(16 + c_l) * MROW + kb];
            short8 a2 = *(const short8*)&Mw[(32 + c_l) * MROW + kb];
            short8 a3 = *(const short8*)&Mw[(48 + c_l) * MROW + kb];
            acc0 = __builtin_amdgcn_mfma_f32_16x16x32_bf16(a0, bf, acc0, 0, 0, 0);
            acc1 = __builtin_amdgcn_mfma_f32_16x16x32_bf16(a1, bf, acc1, 0, 0, 0);
            acc2 = __builtin_amdgcn_mfma_f32_16x16x32_bf16(a2, bf, acc2, 0, 0, 0);
            acc3 = __builtin_amdgcn_mfma_f32_16x16x32_bf16(a3, bf, acc3, 0, 0, 0);
        }

        grp = nxt;
    }

    // C/D layout: col=lane&15, row=(lane>>4)*4+reg (m89-verified).
    // Stage per-wave f32 partial into this wave's (now dead) M region.
    __syncthreads();
    float* Ow = (float*)Mw;   // 9216 B >= 1536 B needed
    if (c_l < NCOMP) {
#pragma unroll
        for (int r = 0; r < 4; ++r) {
            Ow[( 0 + k4 * 4 + r) * NCOMP + c_l] = acc0[r];
            Ow[(16 + k4 * 4 + r) * NCOMP + c_l] = acc1[r];
            Ow[(32 + k4 * 4 + r) * NCOMP + c_l] = acc2[r];
            Ow[(48 + k4 * 4 + r) * NCOMP + c_l] = acc3[r];
        }
    }
    __syncthreads();
    // Atomic epilogue: expand symmetric 6 -> 3x3 and add to out (native
    // agent-scope f32 atomic; 576 adds per block over 36 cachelines).
    for (int i = threadIdx.x; i < NG * 9; i += blockDim.x) {
        int g = i / 9, ij = i % 9, r = ij / 3, cc = ij % 3;
        int lo = r < cc ? r : cc, hi = r < cc ? cc : r;
        int comp = (lo == 0) ? hi : ((lo == 1) ? 2 + hi : 5);
        int k = g * NCOMP + comp;
        float s = ((const float*)Msh[0])[k] + ((const float*)Msh[1])[k]
                + ((const float*)Msh[2])[k] + ((const float*)Msh[3])[k];
        __hip_atomic_fetch_add(&out[i], s, __ATOMIC_RELAXED,
                               __HIP_MEMORY_SCOPE_AGENT);
    }
}

// ---------------- fallback (tiny ws): LDS-atomic path ----------------
__global__ __launch_bounds__(256) void virial_atomic(
    const float* __restrict__ disp, const float* __restrict__ edge_w,
    const int* __restrict__ edge_index, const int* __restrict__ batch,
    float* __restrict__ out, int E)
{
    __shared__ float acc[NG * 7];
    for (int i = threadIdx.x; i < NG * 7; i += blockDim.x) acc[i] = 0.f;
    __syncthreads();
    int tid = blockIdx.x * blockDim.x + threadIdx.x;
    int stride = gridDim.x * blockDim.x;
    for (int e = tid; e < E; e += stride) {
        float d0 = disp[e*3], d1 = disp[e*3+1], d2 = disp[e*3+2];
        float c = -2.f * edge_w[e];
        int g0 = batch[edge_index[e]], g1 = batch[edge_index[E + e]];
        float v[6] = {c*d0*d0, c*d0*d1, c*d0*d2, c*d1*d1, c*d1*d2, c*d2*d2};
#pragma unroll
        for (int k = 0; k < 6; ++k) {
            lds_add(&acc[g0*7+k], v[k]);
            lds_add(&acc[g1*7+k], v[k]);
        }
    }
    __syncthreads();
    for (int i = threadIdx.x; i < NG * 9; i += blockDim.x) {
        int g = i / 9, ij = i % 9, r = ij / 3, cc = ij % 3;
        int lo = r < cc ? r : cc, hi = r < cc ? cc : r;
        int comp = (lo == 0) ? hi : ((lo == 1) ? 2 + hi : 5);
        __hip_atomic_fetch_add(&out[i], acc[g*7+comp], __ATOMIC_RELAXED, __HIP_MEMORY_SCOPE_AGENT);
    }
}

extern "C" void kernel_launch(void* const* d_in, const int* in_sizes, int n_in,
                              void* d_out, int out_size, void* d_ws, size_t ws_size,
                              hipStream_t stream) {
    const float* disp       = (const float*)d_in[0];
    const float* edge_w     = (const float*)d_in[1];
    const int*   edge_index = (const int*)d_in[2];
    const int*   batch      = (const int*)d_in[3];
    float*       out        = (float*)d_out;
    const int E = in_sizes[1];
    const int N = in_sizes[3];

    zero_out_kernel<<<3, 256, 0, stream>>>(out, NG * 9);

    if (ws_size >= 128 * sizeof(int)) {
        int* B = (int*)d_ws;   // [65]
        bounds_build<<<1, 128, 0, stream>>>(batch, B, N);
        virial_mfma<<<MFMA_BLOCKS, 256, 0, stream>>>(disp, edge_w, edge_index, B, out, E);
    } else {
        virial_atomic<<<2048, 256, 0, stream>>>(disp, edge_w, edge_index, batch, out, E);
    }
}

// Round 28
// 38.411 us; speedup vs baseline: 1.4871x; 1.4871x over previous
//
#include <hip/hip_runtime.h>
#include <hip/hip_fp8.h>

// R28: gather-free structure (R22, 39.3us verified) + fp8 M/Dt fragments
// (R13-verified numerics: absmax 512 = e4m3 quantization, threshold 2119).
// R27 lesson: atomic epilogue = +15us (590K native atomics on 576 addrs,
// ~25cy each serialized) -> REVERTED to the R22 reduce tree.
// fp8 + eperm column-interleave: ONE ds_read_b128 per fragment row covers
// both K=32 chunks -> 5 b128/group (was 10), M bytes halved. The DS pipe is
// the binding resource post-gather-fix (~305cy/group model), so this should
// finally show through (R13's loss was gather-masked).

#define NG 64
#define NCOMP 6
#define NPART (NG * NCOMP)      // 384
#define RED1_BLOCKS 64
#define MFMA_BLOCKS 1024        // 4 blocks/CU
#define WPB 4
#define MROWB 80                // 64 + 16 pad bytes; 16B-aligned rows
#define DROWB 80
#define DTROWS 6                // rows 0..5 real; C cols 6..15 discarded

typedef unsigned char  u8_t;
typedef unsigned int   u32_t;
typedef __attribute__((ext_vector_type(2))) long long long2_t;
typedef __attribute__((ext_vector_type(4))) float f32x4;

__device__ __forceinline__ int eperm(int e) {
    return (((e >> 3) & 3) << 4) | (((e >> 5) & 1) << 3) | (e & 7);
}

__device__ __forceinline__ u8_t f2fp8(float f) {
    return (u8_t)__hip_cvt_float_to_fp8(f, __HIP_SATFINITE, __HIP_E4M3);
}

__device__ __forceinline__ void lds_add(float* p, float v) {
    __hip_atomic_fetch_add(p, v, __ATOMIC_RELAXED, __HIP_MEMORY_SCOPE_WORKGROUP);
}

// graph(a) = max{g : Bs[g] <= a}; Bs non-decreasing, Bs[64] = N sentinel.
__device__ __forceinline__ int gsearch(const int* Bs, int a) {
    int lo = 0;
#pragma unroll
    for (int st = 32; st >= 1; st >>= 1)
        lo += (Bs[lo + st] <= a) ? st : 0;
    return lo;
}

// ---------------- bounds table: B[g] = lower_bound(batch, g) ----------------
__global__ void bounds_build(const int* __restrict__ batch, int* __restrict__ B,
                             int N)
{
    int g = threadIdx.x;
    if (g > 64) return;
    int lo = 0, len = N;
    while (len > 0) {
        int half = len >> 1;
        int mid  = lo + half;
        if (batch[mid] < g) { lo = mid + 1; len -= half + 1; }
        else                { len = half; }
    }
    B[g] = lo;   // g=64 -> N (sentinel)
}

// ---------------- MFMA main kernel (fp8 fragments) ----------------
__global__ __launch_bounds__(256) void virial_mfma(
    const float* __restrict__ disp, const float* __restrict__ edge_w,
    const int* __restrict__ edge_index, const int* __restrict__ Bg,
    float* __restrict__ partials, int E)
{
    __shared__ u8_t Msh[WPB][NG * MROWB];       // 4 x 5120 B (reused as f32 stage)
    __shared__ u8_t Dsh[WPB][DTROWS * DROWB];   // 4 x  480 B
    __shared__ int  Bs[65];                     //   260 B

    const int lane = threadIdx.x & 63;
    const int wave = threadIdx.x >> 6;
    u8_t* Mw = Msh[wave];
    u8_t* Dw = Dsh[wave];

    if (threadIdx.x < 65) Bs[threadIdx.x] = Bg[threadIdx.x];
    {   // zero per-wave M and Dt (same-wave DS ops are in order)
        u32_t* p = (u32_t*)Mw;
        for (int i = lane; i < NG * MROWB / 4; i += 64) p[i] = 0u;
        u32_t* q = (u32_t*)Dw;
        for (int i = lane; i < DTROWS * DROWB / 4; i += 64) q[i] = 0u;
    }
    __syncthreads();   // Bs ready

    f32x4 acc0 = {0,0,0,0}, acc1 = {0,0,0,0}, acc2 = {0,0,0,0}, acc3 = {0,0,0,0};
    const int ngroups = (E + 63) >> 6;
    const int gstride = (int)gridDim.x * WPB;
    const int c_l  = lane & 15;
    const int k4   = lane >> 4;
    const int mcol = eperm(lane);                            // storage column
    const int drow = (c_l < DTROWS) ? c_l : (DTROWS - 1);    // junk -> discarded C cols
    int pg0 = 0, pg1 = 0;

    int grp = (int)blockIdx.x * WPB + wave;

    // 1-deep prefetch of the streaming loads (w, disp, idx) — no gathers
    float pw = 0.f, px = 0.f, py = 0.f, pz = 0.f;
    int   ps = 0, pt = 0;
    if (grp < ngroups) {
        int e  = grp * 64 + lane;
        int ec = e < E ? e : E - 1;
        pw = (e < E) ? edge_w[ec] : 0.f;   // w=0 kills clamped-tail terms
        px = disp[ec * 3 + 0];
        py = disp[ec * 3 + 1];
        pz = disp[ec * 3 + 2];
        ps = edge_index[ec];
        pt = edge_index[E + ec];
    }

    while (grp < ngroups) {
        const float w = pw, d0 = px, d1 = py, d2 = pz;
        const int   sC = ps, tC = pt;

        const int nxt = grp + gstride;
        if (nxt < ngroups) {
            int e  = nxt * 64 + lane;
            int ec = e < E ? e : E - 1;
            pw = (e < E) ? edge_w[ec] : 0.f;
            px = disp[ec * 3 + 0];
            py = disp[ec * 3 + 1];
            pz = disp[ec * 3 + 2];
            ps = edge_index[ec];
            pt = edge_index[E + ec];
        }

        // gather-free endpoint->graph: 6-step ladder over LDS table
        const int g0 = gsearch(Bs, sC);
        const int g1 = gsearch(Bs, tC);

        // M one-hot (storage column mcol; plain stores, race-free)
        Mw[pg0 * MROWB + mcol] = 0;
        Mw[pg1 * MROWB + mcol] = 0;
        Mw[g0 * MROWB + mcol] = 0x38u;                         // e4m3 1.0
        Mw[g1 * MROWB + mcol] = (g1 == g0) ? 0x40u : 0x38u;    // e4m3 2.0/1.0
        pg0 = g0; pg1 = g1;

        float cw = -2.f * w;
        Dw[0 * DROWB + mcol] = f2fp8(cw * d0 * d0);
        Dw[1 * DROWB + mcol] = f2fp8(cw * d0 * d1);
        Dw[2 * DROWB + mcol] = f2fp8(cw * d0 * d2);
        Dw[3 * DROWB + mcol] = f2fp8(cw * d1 * d1);
        Dw[4 * DROWB + mcol] = f2fp8(cw * d1 * d2);
        Dw[5 * DROWB + mcol] = f2fp8(cw * d2 * d2);

        // fragments: one b128 per row covers BOTH K=32 chunks (R13-verified)
        long2_t bf = *(const long2_t*)&Dw[drow * DROWB + k4 * 16];
        long2_t a0 = *(const long2_t*)&Mw[( 0 + c_l) * MROWB + k4 * 16];
        long2_t a1 = *(const long2_t*)&Mw[(16 + c_l) * MROWB + k4 * 16];
        long2_t a2 = *(const long2_t*)&Mw[(32 + c_l) * MROWB + k4 * 16];
        long2_t a3 = *(const long2_t*)&Mw[(48 + c_l) * MROWB + k4 * 16];

        acc0 = __builtin_amdgcn_mfma_f32_16x16x32_fp8_fp8(a0[0], bf[0], acc0, 0, 0, 0);
        acc1 = __builtin_amdgcn_mfma_f32_16x16x32_fp8_fp8(a1[0], bf[0], acc1, 0, 0, 0);
        acc2 = __builtin_amdgcn_mfma_f32_16x16x32_fp8_fp8(a2[0], bf[0], acc2, 0, 0, 0);
        acc3 = __builtin_amdgcn_mfma_f32_16x16x32_fp8_fp8(a3[0], bf[0], acc3, 0, 0, 0);
        acc0 = __builtin_amdgcn_mfma_f32_16x16x32_fp8_fp8(a0[1], bf[1], acc0, 0, 0, 0);
        acc1 = __builtin_amdgcn_mfma_f32_16x16x32_fp8_fp8(a1[1], bf[1], acc1, 0, 0, 0);
        acc2 = __builtin_amdgcn_mfma_f32_16x16x32_fp8_fp8(a2[1], bf[1], acc2, 0, 0, 0);
        acc3 = __builtin_amdgcn_mfma_f32_16x16x32_fp8_fp8(a3[1], bf[1], acc3, 0, 0, 0);

        grp = nxt;
    }

    // C/D layout: col=lane&15, row=(lane>>4)*4+reg (dtype-independent).
    // Stage per-wave f32 partial into this wave's (now dead) M region.
    __syncthreads();
    float* Ow = (float*)Mw;   // 5120 B >= 1536 B needed
    if (c_l < NCOMP) {
#pragma unroll
        for (int r = 0; r < 4; ++r) {
            Ow[( 0 + k4 * 4 + r) * NCOMP + c_l] = acc0[r];
            Ow[(16 + k4 * 4 + r) * NCOMP + c_l] = acc1[r];
            Ow[(32 + k4 * 4 + r) * NCOMP + c_l] = acc2[r];
            Ow[(48 + k4 * 4 + r) * NCOMP + c_l] = acc3[r];
        }
    }
    __syncthreads();
    for (int i = threadIdx.x; i < NPART; i += blockDim.x) {
        float s = ((const float*)Msh[0])[i] + ((const float*)Msh[1])[i]
                + ((const float*)Msh[2])[i] + ((const float*)Msh[3])[i];
        partials[(size_t)blockIdx.x * NPART + i] = s;
    }
}

// ---------------- reductions (atomic-free; R22-verified) ----------------
__global__ __launch_bounds__(NPART) void reduce1_kernel(
    const float* __restrict__ partials, float* __restrict__ partials2, int nblk)
{
    int i = threadIdx.x, j = blockIdx.x;
    float s = 0.f;
    for (int b = j; b < nblk; b += RED1_BLOCKS)
        s += partials[(size_t)b * NPART + i];
    partials2[(size_t)j * NPART + i] = s;
}

__global__ __launch_bounds__(NPART) void reduce2_kernel(
    const float* __restrict__ partials2, float* __restrict__ dst)  // dst: 64*9
{
    int i = threadIdx.x;
    float s = 0.f;
#pragma unroll
    for (int j = 0; j < RED1_BLOCKS; ++j)
        s += partials2[(size_t)j * NPART + i];
    int g = i / NCOMP, c = i % NCOMP;
    int r   = (c < 3) ? 0 : ((c < 5) ? 1 : 2);
    int col = (c < 3) ? c : ((c < 5) ? c - 2 : 2);
    dst[g * 9 + r * 3 + col] = s;
    if (r != col) dst[g * 9 + col * 3 + r] = s;
}

// ---------------- fallback (tiny ws): LDS-atomic path ----------------
__global__ void zero_out_kernel(float* __restrict__ out, int n) {
    int i = blockIdx.x * blockDim.x + threadIdx.x;
    if (i < n) out[i] = 0.f;
}

__global__ __launch_bounds__(256) void virial_atomic(
    const float* __restrict__ disp, const float* __restrict__ edge_w,
    const int* __restrict__ edge_index, const int* __restrict__ batch,
    float* __restrict__ out, int E)
{
    __shared__ float acc[NG * 7];
    for (int i = threadIdx.x; i < NG * 7; i += blockDim.x) acc[i] = 0.f;
    __syncthreads();
    int tid = blockIdx.x * blockDim.x + threadIdx.x;
    int stride = gridDim.x * blockDim.x;
    for (int e = tid; e < E; e += stride) {
        float d0 = disp[e*3], d1 = disp[e*3+1], d2 = disp[e*3+2];
        float c = -2.f * edge_w[e];
        int g0 = batch[edge_index[e]], g1 = batch[edge_index[E + e]];
        float v[6] = {c*d0*d0, c*d0*d1, c*d0*d2, c*d1*d1, c*d1*d2, c*d2*d2};
#pragma unroll
        for (int k = 0; k < 6; ++k) {
            lds_add(&acc[g0*7+k], v[k]);
            lds_add(&acc[g1*7+k], v[k]);
        }
    }
    __syncthreads();
    for (int i = threadIdx.x; i < NG * 9; i += blockDim.x) {
        int g = i / 9, ij = i % 9, r = ij / 3, cc = ij % 3;
        int lo = r < cc ? r : cc, hi = r < cc ? cc : r;
        int comp = (lo == 0) ? hi : ((lo == 1) ? 2 + hi : 5);
        __hip_atomic_fetch_add(&out[i], acc[g*7+comp], __ATOMIC_RELAXED, __HIP_MEMORY_SCOPE_AGENT);
    }
}

extern "C" void kernel_launch(void* const* d_in, const int* in_sizes, int n_in,
                              void* d_out, int out_size, void* d_ws, size_t ws_size,
                              hipStream_t stream) {
    const float* disp       = (const float*)d_in[0];
    const float* edge_w     = (const float*)d_in[1];
    const int*   edge_index = (const int*)d_in[2];
    const int*   batch      = (const int*)d_in[3];
    float*       out        = (float*)d_out;
    const int E = in_sizes[1];
    const int N = in_sizes[3];

    const size_t need = (size_t)(MFMA_BLOCKS + RED1_BLOCKS) * NPART * sizeof(float)
                        + 128 * sizeof(int);

    if (ws_size >= need) {
        float* pm = (float*)d_ws;                         // [MFMA_BLOCKS][NPART]
        float* p2 = pm + (size_t)MFMA_BLOCKS * NPART;     // [RED1_BLOCKS][NPART]
        int*   B  = (int*)(p2 + (size_t)RED1_BLOCKS * NPART);   // [65]

        bounds_build<<<1, 128, 0, stream>>>(batch, B, N);
        virial_mfma<<<MFMA_BLOCKS, 256, 0, stream>>>(disp, edge_w, edge_index, B, pm, E);
        reduce1_kernel<<<RED1_BLOCKS, NPART, 0, stream>>>(pm, p2, MFMA_BLOCKS);
        reduce2_kernel<<<1, NPART, 0, stream>>>(p2, out);
    } else {
        zero_out_kernel<<<1, 256, 0, stream>>>(out, NG * 9);
        virial_atomic<<<2048, 256, 0, stream>>>(disp, edge_w, edge_index, batch, out, E);
    }
}

// Round 29
// 36.451 us; speedup vs baseline: 1.5670x; 1.0538x over previous
//
#include <hip/hip_runtime.h>
#include <hip/hip_fp8.h>

// R29 = R28 (38.4us, absmax 512 verified) + two search-side levers:
//  1. estimate-and-verify endpoint->graph: g_est = a*64/N (VALU) + exact
//     correction loops over the LDS table (~8cy/endpoint vs ladder ~35cy;
//     batch is sorted multinomial -> estimate right for ~92% of lanes).
//  2. bounds_build fused into the main-kernel prologue (threads 0..64 do the
//     17-step lower_bound over L2-hot batch once per block) -> -1 launch.
// fp8 M/Dt + eperm + DTROWS clamp + reduce tree byte-identical to R28.

#define NG 64
#define NCOMP 6
#define NPART (NG * NCOMP)      // 384
#define RED1_BLOCKS 64
#define MFMA_BLOCKS 1024        // 4 blocks/CU
#define WPB 4
#define MROWB 80                // 64 + 16 pad bytes; 16B-aligned rows
#define DROWB 80
#define DTROWS 6                // rows 0..5 real; C cols 6..15 discarded

typedef unsigned char  u8_t;
typedef unsigned int   u32_t;
typedef __attribute__((ext_vector_type(2))) long long long2_t;
typedef __attribute__((ext_vector_type(4))) float f32x4;

__device__ __forceinline__ int eperm(int e) {
    return (((e >> 3) & 3) << 4) | (((e >> 5) & 1) << 3) | (e & 7);
}

__device__ __forceinline__ u8_t f2fp8(float f) {
    return (u8_t)__hip_cvt_float_to_fp8(f, __HIP_SATFINITE, __HIP_E4M3);
}

__device__ __forceinline__ void lds_add(float* p, float v) {
    __hip_atomic_fetch_add(p, v, __ATOMIC_RELAXED, __HIP_MEMORY_SCOPE_WORKGROUP);
}

// Estimate-and-verify: g = max{g : Bs[g] <= a}. Bs[0]=0, Bs[64]=N sentinel.
__device__ __forceinline__ int gsearch(const int* Bs, int a, float rcpN) {
    int g = (int)((float)a * rcpN);
    g = g > 63 ? 63 : g;
    while (Bs[g] > a) --g;          // fires for ~4% of lanes
    while (Bs[g + 1] <= a) ++g;     // fires for ~4% of lanes
    return g;
}

// ---------------- MFMA main kernel (fp8 fragments, fused bounds) ----------------
__global__ __launch_bounds__(256) void virial_mfma(
    const float* __restrict__ disp, const float* __restrict__ edge_w,
    const int* __restrict__ edge_index, const int* __restrict__ batch,
    float* __restrict__ partials, int E, int N, float rcpN)
{
    __shared__ u8_t Msh[WPB][NG * MROWB];       // 4 x 5120 B (reused as f32 stage)
    __shared__ u8_t Dsh[WPB][DTROWS * DROWB];   // 4 x  480 B
    __shared__ int  Bs[65];                     //   260 B

    const int lane = threadIdx.x & 63;
    const int wave = threadIdx.x >> 6;
    u8_t* Mw = Msh[wave];
    u8_t* Dw = Dsh[wave];

    // Fused bounds table: Bs[g] = lower_bound(batch, g) (batch sorted, L2-hot)
    if (threadIdx.x < 65) {
        int g = threadIdx.x;
        int lo = 0, len = N;
        while (len > 0) {
            int half = len >> 1;
            int mid  = lo + half;
            if (batch[mid] < g) { lo = mid + 1; len -= half + 1; }
            else                { len = half; }
        }
        Bs[g] = lo;    // g=64 -> N (sentinel)
    }
    {   // zero per-wave M and Dt (same-wave DS ops are in order)
        u32_t* p = (u32_t*)Mw;
        for (int i = lane; i < NG * MROWB / 4; i += 64) p[i] = 0u;
        u32_t* q = (u32_t*)Dw;
        for (int i = lane; i < DTROWS * DROWB / 4; i += 64) q[i] = 0u;
    }
    __syncthreads();   // Bs ready

    f32x4 acc0 = {0,0,0,0}, acc1 = {0,0,0,0}, acc2 = {0,0,0,0}, acc3 = {0,0,0,0};
    const int ngroups = (E + 63) >> 6;
    const int gstride = (int)gridDim.x * WPB;
    const int c_l  = lane & 15;
    const int k4   = lane >> 4;
    const int mcol = eperm(lane);                            // storage column
    const int drow = (c_l < DTROWS) ? c_l : (DTROWS - 1);    // junk -> discarded C cols
    int pg0 = 0, pg1 = 0;

    int grp = (int)blockIdx.x * WPB + wave;

    // 1-deep prefetch of the streaming loads (w, disp, idx) — no gathers
    float pw = 0.f, px = 0.f, py = 0.f, pz = 0.f;
    int   ps = 0, pt = 0;
    if (grp < ngroups) {
        int e  = grp * 64 + lane;
        int ec = e < E ? e : E - 1;
        pw = (e < E) ? edge_w[ec] : 0.f;   // w=0 kills clamped-tail terms
        px = disp[ec * 3 + 0];
        py = disp[ec * 3 + 1];
        pz = disp[ec * 3 + 2];
        ps = edge_index[ec];
        pt = edge_index[E + ec];
    }

    while (grp < ngroups) {
        const float w = pw, d0 = px, d1 = py, d2 = pz;
        const int   sC = ps, tC = pt;

        const int nxt = grp + gstride;
        if (nxt < ngroups) {
            int e  = nxt * 64 + lane;
            int ec = e < E ? e : E - 1;
            pw = (e < E) ? edge_w[ec] : 0.f;
            px = disp[ec * 3 + 0];
            py = disp[ec * 3 + 1];
            pz = disp[ec * 3 + 2];
            ps = edge_index[ec];
            pt = edge_index[E + ec];
        }

        // estimate-and-verify endpoint->graph (exact)
        const int g0 = gsearch(Bs, sC, rcpN);
        const int g1 = gsearch(Bs, tC, rcpN);

        // M one-hot (storage column mcol; plain stores, race-free)
        Mw[pg0 * MROWB + mcol] = 0;
        Mw[pg1 * MROWB + mcol] = 0;
        Mw[g0 * MROWB + mcol] = 0x38u;                         // e4m3 1.0
        Mw[g1 * MROWB + mcol] = (g1 == g0) ? 0x40u : 0x38u;    // e4m3 2.0/1.0
        pg0 = g0; pg1 = g1;

        float cw = -2.f * w;
        Dw[0 * DROWB + mcol] = f2fp8(cw * d0 * d0);
        Dw[1 * DROWB + mcol] = f2fp8(cw * d0 * d1);
        Dw[2 * DROWB + mcol] = f2fp8(cw * d0 * d2);
        Dw[3 * DROWB + mcol] = f2fp8(cw * d1 * d1);
        Dw[4 * DROWB + mcol] = f2fp8(cw * d1 * d2);
        Dw[5 * DROWB + mcol] = f2fp8(cw * d2 * d2);

        // fragments: one b128 per row covers BOTH K=32 chunks (R13-verified)
        long2_t bf = *(const long2_t*)&Dw[drow * DROWB + k4 * 16];
        long2_t a0 = *(const long2_t*)&Mw[( 0 + c_l) * MROWB + k4 * 16];
        long2_t a1 = *(const long2_t*)&Mw[(16 + c_l) * MROWB + k4 * 16];
        long2_t a2 = *(const long2_t*)&Mw[(32 + c_l) * MROWB + k4 * 16];
        long2_t a3 = *(const long2_t*)&Mw[(48 + c_l) * MROWB + k4 * 16];

        acc0 = __builtin_amdgcn_mfma_f32_16x16x32_fp8_fp8(a0[0], bf[0], acc0, 0, 0, 0);
        acc1 = __builtin_amdgcn_mfma_f32_16x16x32_fp8_fp8(a1[0], bf[0], acc1, 0, 0, 0);
        acc2 = __builtin_amdgcn_mfma_f32_16x16x32_fp8_fp8(a2[0], bf[0], acc2, 0, 0, 0);
        acc3 = __builtin_amdgcn_mfma_f32_16x16x32_fp8_fp8(a3[0], bf[0], acc3, 0, 0, 0);
        acc0 = __builtin_amdgcn_mfma_f32_16x16x32_fp8_fp8(a0[1], bf[1], acc0, 0, 0, 0);
        acc1 = __builtin_amdgcn_mfma_f32_16x16x32_fp8_fp8(a1[1], bf[1], acc1, 0, 0, 0);
        acc2 = __builtin_amdgcn_mfma_f32_16x16x32_fp8_fp8(a2[1], bf[1], acc2, 0, 0, 0);
        acc3 = __builtin_amdgcn_mfma_f32_16x16x32_fp8_fp8(a3[1], bf[1], acc3, 0, 0, 0);

        grp = nxt;
    }

    // C/D layout: col=lane&15, row=(lane>>4)*4+reg (dtype-independent).
    // Stage per-wave f32 partial into this wave's (now dead) M region.
    __syncthreads();
    float* Ow = (float*)Mw;   // 5120 B >= 1536 B needed
    if (c_l < NCOMP) {
#pragma unroll
        for (int r = 0; r < 4; ++r) {
            Ow[( 0 + k4 * 4 + r) * NCOMP + c_l] = acc0[r];
            Ow[(16 + k4 * 4 + r) * NCOMP + c_l] = acc1[r];
            Ow[(32 + k4 * 4 + r) * NCOMP + c_l] = acc2[r];
            Ow[(48 + k4 * 4 + r) * NCOMP + c_l] = acc3[r];
        }
    }
    __syncthreads();
    for (int i = threadIdx.x; i < NPART; i += blockDim.x) {
        float s = ((const float*)Msh[0])[i] + ((const float*)Msh[1])[i]
                + ((const float*)Msh[2])[i] + ((const float*)Msh[3])[i];
        partials[(size_t)blockIdx.x * NPART + i] = s;
    }
}

// ---------------- reductions (atomic-free; R22-verified) ----------------
__global__ __launch_bounds__(NPART) void reduce1_kernel(
    const float* __restrict__ partials, float* __restrict__ partials2, int nblk)
{
    int i = threadIdx.x, j = blockIdx.x;
    float s = 0.f;
    for (int b = j; b < nblk; b += RED1_BLOCKS)
        s += partials[(size_t)b * NPART + i];
    partials2[(size_t)j * NPART + i] = s;
}

__global__ __launch_bounds__(NPART) void reduce2_kernel(
    const float* __restrict__ partials2, float* __restrict__ dst)  // dst: 64*9
{
    int i = threadIdx.x;
    float s = 0.f;
#pragma unroll
    for (int j = 0; j < RED1_BLOCKS; ++j)
        s += partials2[(size_t)j * NPART + i];
    int g = i / NCOMP, c = i % NCOMP;
    int r   = (c < 3) ? 0 : ((c < 5) ? 1 : 2);
    int col = (c < 3) ? c : ((c < 5) ? c - 2 : 2);
    dst[g * 9 + r * 3 + col] = s;
    if (r != col) dst[g * 9 + col * 3 + r] = s;
}

// ---------------- fallback (tiny ws): LDS-atomic path ----------------
__global__ void zero_out_kernel(float* __restrict__ out, int n) {
    int i = blockIdx.x * blockDim.x + threadIdx.x;
    if (i < n) out[i] = 0.f;
}

__global__ __launch_bounds__(256) void virial_atomic(
    const float* __restrict__ disp, const float* __restrict__ edge_w,
    const int* __restrict__ edge_index, const int* __restrict__ batch,
    float* __restrict__ out, int E)
{
    __shared__ float acc[NG * 7];
    for (int i = threadIdx.x; i < NG * 7; i += blockDim.x) acc[i] = 0.f;
    __syncthreads();
    int tid = blockIdx.x * blockDim.x + threadIdx.x;
    int stride = gridDim.x * blockDim.x;
    for (int e = tid; e < E; e += stride) {
        float d0 = disp[e*3], d1 = disp[e*3+1], d2 = disp[e*3+2];
        float c = -2.f * edge_w[e];
        int g0 = batch[edge_index[e]], g1 = batch[edge_index[E + e]];
        float v[6] = {c*d0*d0, c*d0*d1, c*d0*d2, c*d1*d1, c*d1*d2, c*d2*d2};
#pragma unroll
        for (int k = 0; k < 6; ++k) {
            lds_add(&acc[g0*7+k], v[k]);
            lds_add(&acc[g1*7+k], v[k]);
        }
    }
    __syncthreads();
    for (int i = threadIdx.x; i < NG * 9; i += blockDim.x) {
        int g = i / 9, ij = i % 9, r = ij / 3, cc = ij % 3;
        int lo = r < cc ? r : cc, hi = r < cc ? cc : r;
        int comp = (lo == 0) ? hi : ((lo == 1) ? 2 + hi : 5);
        __hip_atomic_fetch_add(&out[i], acc[g*7+comp], __ATOMIC_RELAXED, __HIP_MEMORY_SCOPE_AGENT);
    }
}

extern "C" void kernel_launch(void* const* d_in, const int* in_sizes, int n_in,
                              void* d_out, int out_size, void* d_ws, size_t ws_size,
                              hipStream_t stream) {
    const float* disp       = (const float*)d_in[0];
    const float* edge_w     = (const float*)d_in[1];
    const int*   edge_index = (const int*)d_in[2];
    const int*   batch      = (const int*)d_in[3];
    float*       out        = (float*)d_out;
    const int E = in_sizes[1];
    const int N = in_sizes[3];
    const float rcpN = (float)NG / (float)N;

    const size_t need = (size_t)(MFMA_BLOCKS + RED1_BLOCKS) * NPART * sizeof(float);

    if (ws_size >= need) {
        float* pm = (float*)d_ws;                         // [MFMA_BLOCKS][NPART]
        float* p2 = pm + (size_t)MFMA_BLOCKS * NPART;     // [RED1_BLOCKS][NPART]

        virial_mfma<<<MFMA_BLOCKS, 256, 0, stream>>>(disp, edge_w, edge_index,
                                                     batch, pm, E, N, rcpN);
        reduce1_kernel<<<RED1_BLOCKS, NPART, 0, stream>>>(pm, p2, MFMA_BLOCKS);
        reduce2_kernel<<<1, NPART, 0, stream>>>(p2, out);
    } else {
        zero_out_kernel<<<1, 256, 0, stream>>>(out, NG * 9);
        virial_atomic<<<2048, 256, 0, stream>>>(disp, edge_w, edge_index, batch, out, E);
    }
}